// Round 2
// baseline (17.356 us; speedup 1.0000x reference)
//
#include <hip/hip_runtime.h>

#define NG 2048
#define WIMG 256
#define HIMG 256
#define TILE 16
#define CAP 1280
#define LOG2E 1.4426950408889634f
#define LOG2EPS -23.25f   // 2^-23.25 ~ 1e-7 : per-gaussian skip epsilon

// ---------------- one-shot per-gaussian prep (8 blocks x 256) ----------------
// Writes, per gaussian g:
//   p0[g] = (cx, cy, na, nb)     center + folded quadratic coeffs (-log2e * ...)
//   p1[g] = (nc, k,  cr, cg)     k = log2(opacity_sigmoid)
//   p2[g] = (cb, r2max)          r2max: drop gaussian when dist2(tile) > r2max
__global__ __launch_bounds__(256) void gi_prep_kernel(
    const float* __restrict__ xyz,      // (3, N, 2)
    const float* __restrict__ chol,     // (3, N, 3)
    const float* __restrict__ opacity,  // (N, 1)
    const float* __restrict__ feat,     // (N, 3)
    const int*   __restrict__ fidx,
    float4* __restrict__ p0,
    float4* __restrict__ p1,
    float2* __restrict__ p2)
{
    const int g = blockIdx.x * 256 + threadIdx.x;
    const float t  = (float)(*fidx) * (1.0f / 7.0f);   // linspace(0,1,8)[idx]
    const float t2 = t * t;

    const float2* xy2 = (const float2*)xyz;
    float2 a0 = xy2[g];
    float2 a1 = xy2[NG + g];
    float2 a2 = xy2[2 * NG + g];

    float ux = fmaf(t2, a2.x, fmaf(t, a1.x, a0.x));
    float uy = fmaf(t2, a2.y, fmaf(t, a1.y, a0.y));
    // tanh(x) = (e^{2x}-1)/(e^{2x}+1) via native exp2/rcp
    float ex = __builtin_amdgcn_exp2f(2.0f * LOG2E * ux);
    float ey = __builtin_amdgcn_exp2f(2.0f * LOG2E * uy);
    float mx = (ex - 1.0f) * __builtin_amdgcn_rcpf(ex + 1.0f);
    float my = (ey - 1.0f) * __builtin_amdgcn_rcpf(ey + 1.0f);
    float cx = 128.0f * (mx + 1.0f);
    float cy = 128.0f * (my + 1.0f);

    const float* c0 = chol + g * 3;
    float l1 = fmaf(t2, c0[2*NG*3+0], fmaf(t, c0[NG*3+0], c0[0])) + 0.5f;
    float l2 = fmaf(t2, c0[2*NG*3+1], fmaf(t, c0[NG*3+1], c0[1]));
    float l3 = fmaf(t2, c0[2*NG*3+2], fmaf(t, c0[NG*3+2], c0[2])) + 0.5f;

    float s11 = l1 * l1;
    float s12 = l1 * l2;
    float s22 = fmaf(l2, l2, l3 * l3);
    float det = fmaf(s11, s22, -s12 * s12);
    float rdet = __builtin_amdgcn_rcpf(det);
    float A =  s22 * rdet;
    float B = -s12 * rdet;
    float C =  s11 * rdet;

    // sigmoid via native exp2/rcp
    float opac = __builtin_amdgcn_rcpf(1.0f + __builtin_amdgcn_exp2f(-LOG2E * opacity[g]));
    float k  = __builtin_amdgcn_logf(opac);            // log2(opac)
    float na = -0.5f * LOG2E * A;
    float nb = -LOG2E * B;
    float nc = -0.5f * LOG2E * C;

    float cr = __builtin_amdgcn_rcpf(1.0f + __builtin_amdgcn_exp2f(-LOG2E * feat[g*3+0]));
    float cg = __builtin_amdgcn_rcpf(1.0f + __builtin_amdgcn_exp2f(-LOG2E * feat[g*3+1]));
    float cb = __builtin_amdgcn_rcpf(1.0f + __builtin_amdgcn_exp2f(-LOG2E * feat[g*3+2]));

    // lambda_min of precision matrix -> conservative radius^2
    float amc = A - C;
    float lm  = 0.5f * (A + C) - sqrtf(fmaf(0.25f * amc, amc, B * B));
    float r2max = (k - LOG2EPS) * __builtin_amdgcn_rcpf(0.5f * LOG2E * lm);
    if (!(lm > 0.0f)) r2max = 3.4e38f;   // NaN / non-PD safe: keep everywhere

    p0[g] = make_float4(cx, cy, na, nb);
    p1[g] = make_float4(nc, k, cr, cg);
    p2[g] = make_float2(cb, r2max);
}

// ---------------- per-tile render (256 blocks x 256, 16x16 px tiles) ---------
__global__ __launch_bounds__(256) void gi_render_kernel(
    const float4* __restrict__ p0,
    const float4* __restrict__ p1,
    const float2* __restrict__ p2,
    float*        __restrict__ out)
{
    __shared__ float4 sP[CAP];
    __shared__ float4 sQ[CAP];
    __shared__ float  sB[CAP];
    __shared__ int    swcnt[2][4];

    const int tid  = threadIdx.x;
    const int lane = tid & 63;
    const int wid  = tid >> 6;
    const int bx   = blockIdx.x & 15;
    const int by   = blockIdx.x >> 4;
    const int ix   = bx * TILE + (tid & 15);
    const int iy   = by * TILE + (tid >> 4);
    const float px = (float)ix + 0.5f;
    const float py = (float)iy + 0.5f;
    const float tx0 = (float)(bx * TILE), tx1 = tx0 + (float)TILE;
    const float ty0 = (float)(by * TILE), ty1 = ty0 + (float)TILE;

    float accR = 0.0f, accG = 0.0f, accB = 0.0f;
    int cnt = 0;

    auto render = [&](int n) {
#pragma unroll 2
        for (int s = 0; s < n; ++s) {
            float4 P = sP[s];
            float4 Q = sQ[s];
            float  cb = sB[s];
            float dx = px - P.x;
            float dy = py - P.y;
            float arg = fmaf(P.z, dx * dx,
                        fmaf(P.w, dx * dy,
                        fmaf(Q.x, dy * dy, Q.y)));
            float a = fminf(__builtin_amdgcn_exp2f(arg), 0.99f);
            accR = fmaf(a, Q.z, accR);
            accG = fmaf(a, Q.w, accG);
            accB = fmaf(a, cb, accB);
        }
    };

    float4 P0 = p0[tid];
    float4 P1 = p1[tid];
    float2 P2 = p2[tid];

    for (int c = 0; c < NG / 256; ++c) {
        // software prefetch next chunk (loads issue before the barrier below)
        float4 P0n = P0, P1n = P1; float2 P2n = P2;
        if (c + 1 < NG / 256) {
            const int gn = (c + 1) * 256 + tid;
            P0n = p0[gn]; P1n = p1[gn]; P2n = p2[gn];
        }

        // conservative tile cull against precomputed radius^2
        float dxt = fmaxf(fmaxf(tx0 - P0.x, P0.x - tx1), 0.0f);
        float dyt = fmaxf(fmaxf(ty0 - P0.y, P0.y - ty1), 0.0f);
        float d2  = fmaf(dxt, dxt, dyt * dyt);
        bool keep = !(d2 > P2.y);   // NaN-safe: keeps on NaN

        if (cnt + 256 > CAP) {      // overflow fallback; never hit for this data
            __syncthreads();
            render(cnt);
            __syncthreads();
            cnt = 0;
        }

        // deterministic ballot compaction (1 barrier/chunk, parity-buffered counts)
        unsigned long long m = __ballot(keep);
        if (lane == 0) swcnt[c & 1][wid] = __popcll(m);
        __syncthreads();
        int base = cnt;
#pragma unroll
        for (int w = 0; w < 4; ++w)
            if (w < wid) base += swcnt[c & 1][w];
        cnt += swcnt[c & 1][0] + swcnt[c & 1][1] + swcnt[c & 1][2] + swcnt[c & 1][3];
        if (keep) {
            int idx = base + __popcll(m & ((1ULL << lane) - 1ULL));
            sP[idx] = P0;
            sQ[idx] = P1;
            sB[idx] = P2.x;
        }
        P0 = P0n; P1 = P1n; P2 = P2n;
    }

    __syncthreads();   // list writes visible
    render(cnt);

    const int pix = iy * WIMG + ix;
    out[pix]                   = fminf(fmaxf(accR, 0.0f), 1.0f);
    out[HIMG * WIMG + pix]     = fminf(fmaxf(accG, 0.0f), 1.0f);
    out[2 * HIMG * WIMG + pix] = fminf(fmaxf(accB, 0.0f), 1.0f);
}

extern "C" void kernel_launch(void* const* d_in, const int* in_sizes, int n_in,
                              void* d_out, int out_size, void* d_ws, size_t ws_size,
                              hipStream_t stream) {
    const float* xyz     = (const float*)d_in[0];
    const float* chol    = (const float*)d_in[1];
    const float* opacity = (const float*)d_in[2];
    const float* feat    = (const float*)d_in[3];
    const int*   fidx    = (const int*)d_in[4];
    float*       out     = (float*)d_out;

    float4* p0 = (float4*)d_ws;                          // 32 KB
    float4* p1 = (float4*)((char*)d_ws + NG * 16);       // 32 KB
    float2* p2 = (float2*)((char*)d_ws + NG * 32);       // 16 KB

    hipLaunchKernelGGL(gi_prep_kernel, dim3(NG / 256), dim3(256), 0, stream,
                       xyz, chol, opacity, feat, fidx, p0, p1, p2);
    hipLaunchKernelGGL(gi_render_kernel, dim3((WIMG / TILE) * (HIMG / TILE)),
                       dim3(256), 0, stream, p0, p1, p2, out);
}